// Round 15
// baseline (159.204 us; speedup 1.0000x reference)
//
#include <hip/hip_runtime.h>

// TriangleMultiplicativeModule: B=1, L=512, D=H=64, fp32 in/out.
// Pipeline: K0 weight prep -> K1 LN+5 proj (MFMA bf16, B-frags direct from
// global L1/L2, sequential LDS bounce, 37KB LDS -> 4 blocks/CU) -> K2 einsum
// (64x batched 512^3 GEMM, MFMA bf16, 256^2 tiles, global_load_lds staging,
// XCD-grouped) -> K3 out-LN + out proj + gate (direct-global LN reads,
// packed-f16 matvec, fp32 flush).
//
// Global bf16 operand layouts are k-contiguous [h][col][k] with a baked XOR
// swizzle on 16B chunks within each 8-chunk (64-elem) window:
//   chunk position q of row holds k-chunk (q ^ (row&7))
// so LDS staging in K2 is a pure linear copy and ds_read_b128 fragment reads
// are bank-conflict-free.
// ogate layout: [row][col][d] (k3 reads contiguous; k1 stores via LDS bounce).

typedef __attribute__((ext_vector_type(4))) float f32x4;
typedef __attribute__((ext_vector_type(8))) __bf16 bf16x8;
typedef __attribute__((ext_vector_type(2))) _Float16 h2;

__device__ __forceinline__ unsigned short f2bf(float f) {
  unsigned u = __float_as_uint(f);
  u += 0x7FFFu + ((u >> 16) & 1u);   // RNE
  return (unsigned short)(u >> 16);
}
__device__ __forceinline__ float bf2f(unsigned short h) {
  return __uint_as_float(((unsigned)h) << 16);
}
// packed pair-convert: compiler lowers __bf16 casts to v_cvt_pk_bf16_f32 (RNE)
__device__ __forceinline__ unsigned pk2bf(float a, float b) {
  unsigned short ua = __builtin_bit_cast(unsigned short, (__bf16)a);
  unsigned short ub = __builtin_bit_cast(unsigned short, (__bf16)b);
  return (unsigned)ua | ((unsigned)ub << 16);
}
__device__ __forceinline__ float sigm(float x) { return 1.0f / (1.0f + __expf(-x)); }

// ---------------- K0: weight prep (20 blocks) ----------------
// wt[320][64] bf16: rows [left|right|lgate|rgate|ogate]; row n holds W[:,ch]
// k-contiguous, 16B chunks swizzled: pos q holds chunk q^(n&7).
__global__ __launch_bounds__(256) void k0_prep(
    const float* __restrict__ lw, const float* __restrict__ rw,
    const float* __restrict__ lgw, const float* __restrict__ rgw,
    const float* __restrict__ ogw, unsigned short* __restrict__ wt) {
  const int t0 = blockIdx.x * 1024 + threadIdx.x;
  #pragma unroll
  for (int e = 0; e < 4; ++e) {
    int idx = t0 + e * 256;  // [0, 20480)
    int n = idx >> 6, k = idx & 63;
    const float* W = (n < 64) ? lw : (n < 128) ? rw : (n < 192) ? lgw
                     : (n < 256) ? rgw : ogw;
    float v = W[k * 64 + (n & 63)];
    int el = n * 64 + ((((k >> 3) ^ (n & 7)) << 3) | (k & 7));
    wt[el] = f2bf(v);
  }
}

// ---------------- K1: LN + 5 projections + gates + mask ----------------
// Block: 512 threads (8 waves), 128 positions (rows r0..r0+127 at fixed col c).
// Single-pass 20-frag MFMA with B-fragments loaded DIRECTLY from global wt
// (40KB, L1/L2-resident; per-lane 16B loads, same addressing as LDS version).
// No weight LDS -> 37KB total -> 4 blocks/CU (2 grid rounds instead of 4).
// Epilogue: ogate bounced via ldsX; left/right bounced SEQUENTIALLY via one
// 17.4KB buffer; all global stores dense 16B-per-lane runs.
__global__ __launch_bounds__(512) void k1_proj(
    const float* __restrict__ x, const int* __restrict__ smask,
    const float* __restrict__ norm_w, const float* __restrict__ norm_b,
    const float* __restrict__ left_b, const float* __restrict__ right_b,
    const float* __restrict__ lgate_b, const float* __restrict__ rgate_b,
    const float* __restrict__ ogate_b, const unsigned short* __restrict__ wt,
    unsigned short* __restrict__ left_t, unsigned short* __restrict__ right_t,
    unsigned short* __restrict__ ogate) {
  __shared__ __align__(16) char ldsX[16384];   // xn swizzled; reused as OG bounce
  __shared__ __align__(16) char ldsB2[17408];  // left-then-right bounce [64ch][272B]
  __shared__ float sNW[64], sNB[64];
  __shared__ __align__(16) float sLB[64], sRB[64], sLGB[64], sRGB[64], sOGB[64];
  __shared__ float sMK[128];

  const int t = threadIdx.x;
  const int c = blockIdx.x & 511;
  const int r0 = (blockIdx.x >> 9) << 7;

  if (t < 64) {
    sNW[t] = norm_w[t]; sNB[t] = norm_b[t];
    sLB[t] = left_b[t]; sRB[t] = right_b[t];
    sLGB[t] = lgate_b[t]; sRGB[t] = rgate_b[t]; sOGB[t] = ogate_b[t];
  }
  if (t >= 64 && t < 192) sMK[t - 64] = (float)smask[r0 + (t - 64)];
  __syncthreads();

  // phase 1: LayerNorm (4 threads/position, 16 ch each; 128 positions)
  {
    const int m = t >> 2, q = t & 3;
    const float* xp = x + ((size_t)(r0 + m) * 512 + c) * 64 + q * 16;
    float v[16];
    #pragma unroll
    for (int i = 0; i < 4; ++i) {
      float4 f = *(const float4*)(xp + i * 4);
      v[i*4+0] = f.x; v[i*4+1] = f.y; v[i*4+2] = f.z; v[i*4+3] = f.w;
    }
    float s = 0.f, ss = 0.f;
    #pragma unroll
    for (int i = 0; i < 16; ++i) { s += v[i]; ss += v[i] * v[i]; }
    s += __shfl_xor(s, 1); s += __shfl_xor(s, 2);
    ss += __shfl_xor(ss, 1); ss += __shfl_xor(ss, 2);
    const float mu = s * 0.015625f;
    const float rs = rsqrtf(ss * 0.015625f - mu * mu + 1e-5f);
    unsigned pk[8];
    #pragma unroll
    for (int i = 0; i < 8; ++i) {
      const int d0 = q * 16 + 2 * i;
      pk[i] = pk2bf((v[2*i]   - mu) * rs * sNW[d0]     + sNB[d0],
                    (v[2*i+1] - mu) * rs * sNW[d0 + 1] + sNB[d0 + 1]);
    }
    uint4 lo; lo.x = pk[0]; lo.y = pk[1]; lo.z = pk[2]; lo.w = pk[3];
    uint4 hi; hi.x = pk[4]; hi.y = pk[5]; hi.z = pk[6]; hi.w = pk[7];
    *(uint4*)(ldsX + m * 128 + (((q * 2)     ^ (m & 7)) << 4)) = lo;
    *(uint4*)(ldsX + m * 128 + (((q * 2 + 1) ^ (m & 7)) << 4)) = hi;
  }
  __syncthreads();

  // phase 2: MFMA  out[m][n] = xn[m][k] @ W[k][n], n in [0,320)
  // A-frags from ldsX; B-frags per-lane from GLOBAL wt (L1/L2-resident).
  // nf 0..15: D[pos][n] (A=xn, B=W). nf 16..19 (ogate): SWAPPED -> D[d][pos].
  const int w = t >> 6, l = t & 63, lr = l & 15, g = l >> 4;
  const char* wtc = (const char*)wt;
  f32x4 acc[20];
  #pragma unroll
  for (int nf = 0; nf < 20; ++nf) acc[nf] = (f32x4){0.f, 0.f, 0.f, 0.f};
  const int rowA = w * 16 + lr;
  #pragma unroll
  for (int s = 0; s < 2; ++s) {
    const int soff = (((s * 4 + g) ^ (lr & 7)) << 4);
    bf16x8 a = *(const bf16x8*)(ldsX + rowA * 128 + soff);
    #pragma unroll
    for (int nf = 0; nf < 16; ++nf) {
      bf16x8 bb = *(const bf16x8*)(wtc + (nf * 16 + lr) * 128 + soff);
      acc[nf] = __builtin_amdgcn_mfma_f32_16x16x32_bf16(a, bb, acc[nf], 0, 0, 0);
    }
    #pragma unroll
    for (int nf = 16; nf < 20; ++nf) {
      bf16x8 bb = *(const bf16x8*)(wtc + (nf * 16 + lr) * 128 + soff);
      acc[nf] = __builtin_amdgcn_mfma_f32_16x16x32_bf16(bb, a, acc[nf], 0, 0, 0);
    }
  }
  __syncthreads();   // all ldsX reads done -> reusable as ogate bounce

  // epilogue compute (left/right/ogate), keep rpk in regs for later bounce
  uint2 lpk[4], rpk[4];
  {
    const float mc = (float)smask[c];
    float mk[4];
    #pragma unroll
    for (int rr = 0; rr < 4; ++rr) mk[rr] = mc * sMK[w * 16 + g * 4 + rr];
    #pragma unroll
    for (int nf = 0; nf < 4; ++nf) {
      const int hh = nf * 16 + lr;
      const float lb = sLB[hh], rb = sRB[hh];
      const float lgb = sLGB[hh], rgb = sRGB[hh];
      float lo[4], ro[4];
      #pragma unroll
      for (int rr = 0; rr < 4; ++rr) {
        lo[rr] = (acc[nf][rr]     + lb) * mk[rr] * sigm(acc[8  + nf][rr] + lgb);
        ro[rr] = (acc[4 + nf][rr] + rb) * mk[rr] * sigm(acc[12 + nf][rr] + rgb);
      }
      lpk[nf].x = pk2bf(lo[0], lo[1]); lpk[nf].y = pk2bf(lo[2], lo[3]);
      rpk[nf].x = pk2bf(ro[0], ro[1]); rpk[nf].y = pk2bf(ro[2], ro[3]);
    }
    // left -> ldsB2, ogate -> ldsX
    const int rb2 = (w * 16 + g * 4) * 2;
    #pragma unroll
    for (int nf = 0; nf < 4; ++nf)
      *(uint2*)(ldsB2 + (nf * 16 + lr) * 272 + rb2) = lpk[nf];
    const int rloc = w * 16 + lr;
    #pragma unroll
    for (int nf = 0; nf < 4; ++nf) {
      const int d0 = nf * 16 + g * 4;
      const float4 ob4 = *(const float4*)&sOGB[d0];
      const float g0 = sigm(acc[16 + nf][0] + ob4.x);
      const float g1 = sigm(acc[16 + nf][1] + ob4.y);
      const float g2 = sigm(acc[16 + nf][2] + ob4.z);
      const float g3 = sigm(acc[16 + nf][3] + ob4.w);
      uint2 gv; gv.x = pk2bf(g0, g1); gv.y = pk2bf(g2, g3);
      const int slot = (d0 >> 3) ^ (rloc & 7);
      *(uint2*)(ldsX + rloc * 128 + slot * 16 + (d0 & 4) * 2) = gv;
    }
  }
  __syncthreads();

  // store left (dense 16B) + ogate ([row][col][d], 128B runs)
  const int cx = c & 7;
  #pragma unroll
  for (int it = 0; it < 2; ++it) {
    const int idx = it * 512 + t;            // [0,1024)
    const int hh = idx >> 4, rel = idx & 15;
    const size_t goff = (size_t)hh * 524288 + (size_t)c * 1024 +
                        (size_t)(((r0 >> 3) + (rel & 8) + ((rel & 7) ^ cx)) << 4);
    *(uint4*)((char*)left_t + goff) = *(const uint4*)(ldsB2 + hh * 272 + rel * 16);
  }
  #pragma unroll
  for (int it = 0; it < 2; ++it) {
    const int idx = it * 512 + t;            // [0,1024)
    const int rl = idx >> 3, ch = idx & 7;
    *(uint4*)((char*)ogate + ((size_t)(r0 + rl) * 512 + c) * 128 + ch * 16) =
        *(const uint4*)(ldsX + rl * 128 + ((ch ^ (rl & 7)) << 4));
  }
  __syncthreads();

  // bounce right -> ldsB2, then store
  {
    const int rb2 = (w * 16 + g * 4) * 2;
    #pragma unroll
    for (int nf = 0; nf < 4; ++nf)
      *(uint2*)(ldsB2 + (nf * 16 + lr) * 272 + rb2) = rpk[nf];
  }
  __syncthreads();
  #pragma unroll
  for (int it = 0; it < 2; ++it) {
    const int idx = it * 512 + t;            // [0,1024)
    const int hh = idx >> 4, rel = idx & 15;
    const size_t goff = (size_t)hh * 524288 + (size_t)c * 1024 +
                        (size_t)(((r0 >> 3) + (rel & 8) + ((rel & 7) ^ cx)) << 4);
    *(uint4*)((char*)right_t + goff) = *(const uint4*)(ldsB2 + hh * 272 + rel * 16);
  }
}

// ---------------- K2: einsum  o[d][i][j] = sum_k right_t[d][i][k]*left_t[d][j][k]
// 256x256 tiles. global_load_lds staging (linear dest = wave base + lane*16).
// XCD grouping: same-d quadrants dispatch to one XCD (share operand panels in
// its L2). Epilogue: bounce 128-row halves through dead LDS -> 16B stores in
// 512B segments instead of 128 scalar 2B scatters.
__global__ __launch_bounds__(512) void k2_einsum(
    const unsigned short* __restrict__ left_t,
    const unsigned short* __restrict__ right_t,
    unsigned short* __restrict__ o) {
  __shared__ __align__(16) char lds[69632];   // A[0:32K] B[32K:64K]; bounce [128][544]
  char* ldsA = lds;
  char* ldsB = lds + 32768;
  const int t = threadIdx.x;
  const int bid = (int)blockIdx.x;
  const int id = ((bid & 7) << 5) | (bid >> 3);  // round-robin slot -> XCD group
  const int d = id >> 2;
  const int i0 = ((id >> 1) & 1) * 256;
  const int j0 = (id & 1) * 256;
  const int w = t >> 6, l = t & 63, lr = l & 15, g = l >> 4;
  const char* Rb = (const char*)right_t + (size_t)d * 524288;
  const char* Lb = (const char*)left_t  + (size_t)d * 524288;
  f32x4 acc[8][4];
  #pragma unroll
  for (int mi = 0; mi < 8; ++mi)
    #pragma unroll
    for (int nj = 0; nj < 4; ++nj) acc[mi][nj] = (f32x4){0.f, 0.f, 0.f, 0.f};
  const int wm0 = (w >> 2) * 128, wn0 = (w & 3) * 64;
  for (int kb = 0; kb < 512; kb += 64) {
    // stage via global_load_lds: dest = (w*4+cc)*1024 + lane*16 (linear)
    #pragma unroll
    for (int cc = 0; cc < 4; ++cc) {
      const int p16 = (w * 4 + cc) * 64 + l;   // [0,2048)
      const int m = p16 >> 3, sl = p16 & 7;
      __builtin_amdgcn_global_load_lds(
          (const void*)(Rb + (size_t)(i0 + m) * 1024 + kb * 2 + sl * 16),
          (void*)(ldsA + p16 * 16), 16, 0, 0);
      __builtin_amdgcn_global_load_lds(
          (const void*)(Lb + (size_t)(j0 + m) * 1024 + kb * 2 + sl * 16),
          (void*)(ldsB + p16 * 16), 16, 0, 0);
    }
    __syncthreads();
    #pragma unroll
    for (int s = 0; s < 2; ++s) {
      const int soff = (((s * 4 + g) ^ (lr & 7)) << 4);
      bf16x8 af[8], bfr[4];
      #pragma unroll
      for (int mi = 0; mi < 8; ++mi)
        af[mi] = *(const bf16x8*)(ldsA + (wm0 + mi * 16 + lr) * 128 + soff);
      #pragma unroll
      for (int nj = 0; nj < 4; ++nj)
        bfr[nj] = *(const bf16x8*)(ldsB + (wn0 + nj * 16 + lr) * 128 + soff);
      #pragma unroll
      for (int mi = 0; mi < 8; ++mi)
        #pragma unroll
        for (int nj = 0; nj < 4; ++nj)
          acc[mi][nj] = __builtin_amdgcn_mfma_f32_16x16x32_bf16(
              af[mi], bfr[nj], acc[mi][nj], 0, 0, 0);
    }
    __syncthreads();
  }
  // epilogue: two 128-row halves bounced through LDS ([128][544], bank-clean)
  #pragma unroll
  for (int h2i = 0; h2i < 2; ++h2i) {
    if ((w >> 2) == h2i) {
      #pragma unroll
      for (int mi = 0; mi < 8; ++mi)
        #pragma unroll
        for (int nj = 0; nj < 4; ++nj)
          #pragma unroll
          for (int rr = 0; rr < 4; ++rr) {
            const int rl = mi * 16 + g * 4 + rr;       // local row in half
            const int col = wn0 + nj * 16 + lr;
            *(unsigned short*)(lds + rl * 544 + col * 2) = f2bf(acc[mi][nj][rr]);
          }
    }
    __syncthreads();
    #pragma unroll
    for (int it = 0; it < 8; ++it) {
      const int q = it * 512 + t;                      // [0,4096)
      const int rl = q >> 5, ch = q & 31;
      *(uint4*)((char*)o + (size_t)d * 524288 +
                (size_t)(i0 + h2i * 128 + rl) * 1024 + (size_t)j0 * 2 + ch * 16) =
          *(const uint4*)(lds + rl * 544 + ch * 16);
    }
    __syncthreads();
  }
}

// ---------------- K3: out-LN + out projection + out_gate ---------------------
// Direct-global LN reads (bit-identical values; 64B coalesced segments per
// d-plane, L3-resident, hoisted above W staging). No ldsO -> LDS ~10KB.
// Packed-f16 matvec with fp32 flush every 16 k.
__global__ __launch_bounds__(256) void k3_final(
    const unsigned short* __restrict__ o, const unsigned short* __restrict__ ogate,
    const float* __restrict__ onorm_w, const float* __restrict__ onorm_b,
    const float* __restrict__ out_w, const float* __restrict__ out_b,
    float* __restrict__ out) {
  __shared__ __align__(16) _Float16 ldsW[64 * 72];    // [64 k][64 n + 8 pad] f16
  __shared__ float sONW[64], sONB[64], sOB[64];
  const int t = threadIdx.x;
  const int i = blockIdx.x >> 2;
  const int j0 = (blockIdx.x & 3) << 7;
  const size_t p0 = (size_t)i * 512 + j0;
  const int p = t >> 1, h = t & 1;

  // LN input loads FIRST: latency hides under W staging + barrier.
  float v[32];
  {
    const unsigned short* op0 = o + (size_t)(h * 32) * 262144 + p0 + p;
    #pragma unroll
    for (int dl = 0; dl < 32; ++dl)
      v[dl] = bf2f(op0[(size_t)dl * 262144]);
  }

  // stage out_w as f16: ldsW[k*72+n]  (RNE; f16 rel err 2^-11, negligible)
  #pragma unroll
  for (int e = 0; e < 16; ++e) {
    const int idx = e * 256 + t;
    ldsW[(idx >> 6) * 72 + (idx & 63)] = (_Float16)out_w[idx];
  }
  if (t < 64) { sONW[t] = onorm_w[t]; sONB[t] = onorm_b[t]; sOB[t] = out_b[t]; }
  __syncthreads();

  // LN stats (pair reduce)
  float s = 0.f, ss = 0.f;
  #pragma unroll
  for (int dl = 0; dl < 32; ++dl) { s += v[dl]; ss += v[dl] * v[dl]; }
  s += __shfl_xor(s, 1); ss += __shfl_xor(ss, 1);
  const float mu = s * 0.015625f;
  const float rs = rsqrtf(ss * 0.015625f - mu * mu + 1e-5f);
  float xv[32];
  #pragma unroll
  for (int dl = 0; dl < 32; ++dl) {
    const int d = h * 32 + dl;
    xv[dl] = (v[dl] - mu) * rs * sONW[d] + sONB[d];
  }

  // matvec: out[p][n0..n0+31] = sum_k xn[p][k] * W[k][n], packed f16
  const int n0 = h * 32;
  _Float16 xA[32], xB[32];   // own k-half / partner k-half (static indexing)
  #pragma unroll
  for (int dl = 0; dl < 32; ++dl) {
    xA[dl] = (_Float16)xv[dl];
    xB[dl] = (_Float16)__shfl_xor(xv[dl], 1);
  }
  float acc[32];
  #pragma unroll
  for (int n = 0; n < 32; ++n) acc[n] = 0.f;
  const int kO = h * 32, kP = (1 - h) * 32;
  #pragma unroll
  for (int pb = 0; pb < 4; ++pb) {       // pb 0,1: own half; 2,3: partner half
    h2 acc2[16];
    #pragma unroll
    for (int n2 = 0; n2 < 16; ++n2) { acc2[n2][0] = (_Float16)0.f; acc2[n2][1] = (_Float16)0.f; }
    #pragma unroll
    for (int kk = 0; kk < 16; ++kk) {
      const int ko = (pb & 1) * 16 + kk;                 // compile-time
      const _Float16 av = (pb < 2) ? xA[ko] : xB[ko];    // compile-time select
      const int k = ((pb < 2) ? kO : kP) + ko;
      h2 a2; a2[0] = av; a2[1] = av;
      const uint4* wr = (const uint4*)(ldsW + k * 72 + n0);  // 144B rows, 16B-aligned
      const uint4 w0 = wr[0], w1 = wr[1], w2 = wr[2], w3 = wr[3];
      const unsigned wu[16] = {w0.x, w0.y, w0.z, w0.w, w1.x, w1.y, w1.z, w1.w,
                               w2.x, w2.y, w2.z, w2.w, w3.x, w3.y, w3.z, w3.w};
      #pragma unroll
      for (int n2 = 0; n2 < 16; ++n2)
        acc2[n2] = a2 * __builtin_bit_cast(h2, wu[n2]) + acc2[n2];  // v_pk_fma_f16
    }
    #pragma unroll
    for (int n2 = 0; n2 < 16; ++n2) {       // fp32 flush every 16 k
      acc[2 * n2]     += (float)acc2[n2][0];
      acc[2 * n2 + 1] += (float)acc2[n2][1];
    }
  }

  // epilogue: +out_b, *ogate (bf16, contiguous per position), fp32 store
  const size_t pl = p0 + p;
  const unsigned short* gp = ogate + pl * 64 + n0;
  float* op = out + pl * 64 + n0;
  #pragma unroll
  for (int c = 0; c < 4; ++c) {
    const uint4 g4 = *(const uint4*)(gp + c * 8);
    const unsigned gg[4] = {g4.x, g4.y, g4.z, g4.w};
    float r[8];
    #pragma unroll
    for (int e = 0; e < 4; ++e) {
      r[2*e]   = (acc[c*8 + 2*e]   + sOB[n0 + c*8 + 2*e])   *
                 bf2f((unsigned short)(gg[e] & 0xffffu));
      r[2*e+1] = (acc[c*8 + 2*e+1] + sOB[n0 + c*8 + 2*e+1]) *
                 bf2f((unsigned short)(gg[e] >> 16));
    }
    float4 s0; s0.x = r[0]; s0.y = r[1]; s0.z = r[2]; s0.w = r[3];
    float4 s1; s1.x = r[4]; s1.y = r[5]; s1.z = r[6]; s1.w = r[7];
    *(float4*)(op + c * 8)     = s0;
    *(float4*)(op + c * 8 + 4) = s1;
  }
}

extern "C" void kernel_launch(void* const* d_in, const int* in_sizes, int n_in,
                              void* d_out, int out_size, void* d_ws, size_t ws_size,
                              hipStream_t stream) {
  const float* x       = (const float*)d_in[0];
  const int*   sm      = (const int*)d_in[1];
  const float* norm_w  = (const float*)d_in[2];
  const float* norm_b  = (const float*)d_in[3];
  const float* left_w  = (const float*)d_in[4];
  const float* left_b  = (const float*)d_in[5];
  const float* right_w = (const float*)d_in[6];
  const float* right_b = (const float*)d_in[7];
  const float* lgate_w = (const float*)d_in[8];
  const float* lgate_b = (const float*)d_in[9];
  const float* rgate_w = (const float*)d_in[10];
  const float* rgate_b = (const float*)d_in[11];
  const float* ogate_w = (const float*)d_in[12];
  const float* ogate_b = (const float*)d_in[13];
  const float* onorm_w = (const float*)d_in[14];
  const float* onorm_b = (const float*)d_in[15];
  const float* out_w   = (const float*)d_in[16];
  const float* out_b   = (const float*)d_in[17];

  char* ws = (char*)d_ws;
  unsigned short* left_t  = (unsigned short*)(ws + 0);          // 33.5 MB
  unsigned short* right_t = (unsigned short*)(ws + 33554432);   // 33.5 MB
  unsigned short* ogate   = (unsigned short*)(ws + 67108864);   // 33.5 MB
  unsigned short* obuf    = (unsigned short*)(ws + 100663296);  // 33.5 MB
  unsigned short* wt      = (unsigned short*)(ws + 134217728);  // 40 KB

  if (ws_size < (size_t)134217728 + 40960) return;  // scratch too small

  k0_prep<<<dim3(20), dim3(256), 0, stream>>>(left_w, right_w, lgate_w, rgate_w,
                                              ogate_w, wt);
  k1_proj<<<dim3(2048), dim3(512), 0, stream>>>(x, sm, norm_w, norm_b, left_b,
                                                right_b, lgate_b, rgate_b,
                                                ogate_b, wt, left_t, right_t,
                                                ogate);
  k2_einsum<<<dim3(256), dim3(512), 0, stream>>>(left_t, right_t, obuf);
  k3_final<<<dim3(2048), dim3(256), 0, stream>>>(obuf, ogate, onorm_w, onorm_b,
                                                 out_w, out_b, (float*)d_out);
}

// Round 16
// 122.089 us; speedup vs baseline: 1.3040x; 1.3040x over previous
//
#include <hip/hip_runtime.h>

// TriangleMultiplicativeModule: B=1, L=512, D=H=64, fp32 in/out.
// Pipeline: K0 weight prep -> K1 LN+5 proj (MFMA bf16, async weight staging
// via global_load_lds overlapped with LN, LDS-bounced coalesced stores) ->
// K2 einsum (64x batched 512^3 GEMM, MFMA bf16, 256^2 tiles, global_load_lds
// staging, XCD-grouped) -> K3 out-LN + out proj + gate (direct-global LN
// reads, packed-f16 matvec, fp32 flush).
//
// Global bf16 operand layouts are k-contiguous [h][col][k] with a baked XOR
// swizzle on 16B chunks within each 8-chunk (64-elem) window:
//   chunk position q of row holds k-chunk (q ^ (row&7))
// so LDS staging in K2 is a pure linear copy and ds_read_b128 fragment reads
// are bank-conflict-free.
// ogate layout: [row][col][d] (k3 reads contiguous; k1 stores via LDS bounce).

typedef __attribute__((ext_vector_type(4))) float f32x4;
typedef __attribute__((ext_vector_type(8))) __bf16 bf16x8;
typedef __attribute__((ext_vector_type(2))) _Float16 h2;

__device__ __forceinline__ unsigned short f2bf(float f) {
  unsigned u = __float_as_uint(f);
  u += 0x7FFFu + ((u >> 16) & 1u);   // RNE
  return (unsigned short)(u >> 16);
}
__device__ __forceinline__ float bf2f(unsigned short h) {
  return __uint_as_float(((unsigned)h) << 16);
}
// packed pair-convert: compiler lowers __bf16 casts to v_cvt_pk_bf16_f32 (RNE)
__device__ __forceinline__ unsigned pk2bf(float a, float b) {
  unsigned short ua = __builtin_bit_cast(unsigned short, (__bf16)a);
  unsigned short ub = __builtin_bit_cast(unsigned short, (__bf16)b);
  return (unsigned)ua | ((unsigned)ub << 16);
}
__device__ __forceinline__ float sigm(float x) { return 1.0f / (1.0f + __expf(-x)); }

// ---------------- K0: weight prep (20 blocks) ----------------
// wt[320][64] bf16: rows [left|right|lgate|rgate|ogate]; row n holds W[:,ch]
// k-contiguous, 16B chunks swizzled: pos q holds chunk q^(n&7).
__global__ __launch_bounds__(256) void k0_prep(
    const float* __restrict__ lw, const float* __restrict__ rw,
    const float* __restrict__ lgw, const float* __restrict__ rgw,
    const float* __restrict__ ogw, unsigned short* __restrict__ wt) {
  const int t0 = blockIdx.x * 1024 + threadIdx.x;
  #pragma unroll
  for (int e = 0; e < 4; ++e) {
    int idx = t0 + e * 256;  // [0, 20480)
    int n = idx >> 6, k = idx & 63;
    const float* W = (n < 64) ? lw : (n < 128) ? rw : (n < 192) ? lgw
                     : (n < 256) ? rgw : ogw;
    float v = W[k * 64 + (n & 63)];
    int el = n * 64 + ((((k >> 3) ^ (n & 7)) << 3) | (k & 7));
    wt[el] = f2bf(v);
  }
}

// ---------------- K1: LN + 5 projections + gates + mask ----------------
// Block: 512 threads (8 waves), 128 positions (rows r0..r0+127 at fixed col c).
// Weights streamed async via global_load_lds UNDER the LN phase (no barrier
// between staging and LN: LN reads norm_w/norm_b from global). 5 barriers.
// Single-pass 20-frag MFMA. Epilogue bounces results through dead LDS so all
// global stores are dense 16B-per-lane runs.
__global__ __launch_bounds__(512) void k1_proj(
    const float* __restrict__ x, const int* __restrict__ smask,
    const float* __restrict__ norm_w, const float* __restrict__ norm_b,
    const float* __restrict__ left_b, const float* __restrict__ right_b,
    const float* __restrict__ lgate_b, const float* __restrict__ rgate_b,
    const float* __restrict__ ogate_b, const unsigned short* __restrict__ wt,
    unsigned short* __restrict__ left_t, unsigned short* __restrict__ right_t,
    unsigned short* __restrict__ ogate) {
  __shared__ __align__(16) char ldsWt[40960];  // weights; reused as L/R bounce
  __shared__ __align__(16) char ldsX[16384];   // xn swizzled; reused as OG bounce
  __shared__ __align__(16) float sLB[64], sRB[64], sLGB[64], sRGB[64], sOGB[64];
  __shared__ float sMK[128];

  const int t = threadIdx.x;
  const int c = blockIdx.x & 511;
  const int r0 = (blockIdx.x >> 9) << 7;

  // async weight staging: streams under the LN phase, drained by barrier 1
  #pragma unroll
  for (int i = 0; i < 5; ++i) {
    const int u = t + i * 512;
    __builtin_amdgcn_global_load_lds((const void*)((const char*)wt + u * 16),
                                     (void*)(ldsWt + u * 16), 16, 0, 0);
  }
  if (t < 64) {
    sLB[t] = left_b[t]; sRB[t] = right_b[t];
    sLGB[t] = lgate_b[t]; sRGB[t] = rgate_b[t]; sOGB[t] = ogate_b[t];
  }
  if (t >= 64 && t < 192) sMK[t - 64] = (float)smask[r0 + (t - 64)];

  // phase 1: LayerNorm (4 threads/position, 16 ch each; 128 positions)
  // norm_w/norm_b read from global (L1 broadcast) -> no LDS dependency here.
  {
    const int m = t >> 2, q = t & 3;
    const float* xp = x + ((size_t)(r0 + m) * 512 + c) * 64 + q * 16;
    float v[16];
    #pragma unroll
    for (int i = 0; i < 4; ++i) {
      float4 f = *(const float4*)(xp + i * 4);
      v[i*4+0] = f.x; v[i*4+1] = f.y; v[i*4+2] = f.z; v[i*4+3] = f.w;
    }
    float s = 0.f, ss = 0.f;
    #pragma unroll
    for (int i = 0; i < 16; ++i) { s += v[i]; ss += v[i] * v[i]; }
    s += __shfl_xor(s, 1); s += __shfl_xor(s, 2);
    ss += __shfl_xor(ss, 1); ss += __shfl_xor(ss, 2);
    const float mu = s * 0.015625f;
    const float rs = rsqrtf(ss * 0.015625f - mu * mu + 1e-5f);
    unsigned pk[8];
    #pragma unroll
    for (int i = 0; i < 8; ++i) {
      const int d0 = q * 16 + 2 * i;
      pk[i] = pk2bf((v[2*i]   - mu) * rs * norm_w[d0]     + norm_b[d0],
                    (v[2*i+1] - mu) * rs * norm_w[d0 + 1] + norm_b[d0 + 1]);
    }
    uint4 lo; lo.x = pk[0]; lo.y = pk[1]; lo.z = pk[2]; lo.w = pk[3];
    uint4 hi; hi.x = pk[4]; hi.y = pk[5]; hi.z = pk[6]; hi.w = pk[7];
    *(uint4*)(ldsX + m * 128 + (((q * 2)     ^ (m & 7)) << 4)) = lo;
    *(uint4*)(ldsX + m * 128 + (((q * 2 + 1) ^ (m & 7)) << 4)) = hi;
  }
  __syncthreads();   // drains weight stream + ldsX + const stages

  // phase 2: MFMA  out[m][n] = xn[m][k] @ W[k][n], n in [0,320)
  // nf 0..15: D[pos][n] (A=xn, B=W). nf 16..19 (ogate): SWAPPED -> D[d][pos].
  const int w = t >> 6, l = t & 63, lr = l & 15, g = l >> 4;
  f32x4 acc[20];
  #pragma unroll
  for (int nf = 0; nf < 20; ++nf) acc[nf] = (f32x4){0.f, 0.f, 0.f, 0.f};
  const int rowA = w * 16 + lr;
  #pragma unroll
  for (int s = 0; s < 2; ++s) {
    const int soff = (((s * 4 + g) ^ (lr & 7)) << 4);
    bf16x8 a = *(const bf16x8*)(ldsX + rowA * 128 + soff);
    #pragma unroll
    for (int nf = 0; nf < 16; ++nf) {
      bf16x8 bb = *(const bf16x8*)(ldsWt + (nf * 16 + lr) * 128 + soff);
      acc[nf] = __builtin_amdgcn_mfma_f32_16x16x32_bf16(a, bb, acc[nf], 0, 0, 0);
    }
    #pragma unroll
    for (int nf = 16; nf < 20; ++nf) {
      bf16x8 bb = *(const bf16x8*)(ldsWt + (nf * 16 + lr) * 128 + soff);
      acc[nf] = __builtin_amdgcn_mfma_f32_16x16x32_bf16(bb, a, acc[nf], 0, 0, 0);
    }
  }
  __syncthreads();   // all MFMA LDS reads done -> ldsWt/ldsX reusable

  // epilogue compute -> LDS bounce
  char* bL = ldsWt;            // [64 ch][272B] (128 pos bf16 + 16B pad)
  char* bR = ldsWt + 17408;    // [64 ch][272B]
  {
    const float mc = (float)smask[c];
    float mk[4];
    #pragma unroll
    for (int rr = 0; rr < 4; ++rr) mk[rr] = mc * sMK[w * 16 + g * 4 + rr];
    const int rb2 = (w * 16 + g * 4) * 2;
    #pragma unroll
    for (int nf = 0; nf < 4; ++nf) {
      const int hh = nf * 16 + lr;
      const float lb = sLB[hh], rb = sRB[hh];
      const float lgb = sLGB[hh], rgb = sRGB[hh];
      float lo[4], ro[4];
      #pragma unroll
      for (int rr = 0; rr < 4; ++rr) {
        lo[rr] = (acc[nf][rr]     + lb) * mk[rr] * sigm(acc[8  + nf][rr] + lgb);
        ro[rr] = (acc[4 + nf][rr] + rb) * mk[rr] * sigm(acc[12 + nf][rr] + rgb);
      }
      uint2 lv; lv.x = pk2bf(lo[0], lo[1]); lv.y = pk2bf(lo[2], lo[3]);
      uint2 rv; rv.x = pk2bf(ro[0], ro[1]); rv.y = pk2bf(ro[2], ro[3]);
      *(uint2*)(bL + hh * 272 + rb2) = lv;
      *(uint2*)(bR + hh * 272 + rb2) = rv;
    }
    // ogate bounce: [128 r][64 d] in ldsX, 16B chunks XOR-swizzled by (r&7)
    const int rloc = w * 16 + lr;
    #pragma unroll
    for (int nf = 0; nf < 4; ++nf) {
      const int d0 = nf * 16 + g * 4;
      const float4 ob4 = *(const float4*)&sOGB[d0];
      const float g0 = sigm(acc[16 + nf][0] + ob4.x);
      const float g1 = sigm(acc[16 + nf][1] + ob4.y);
      const float g2 = sigm(acc[16 + nf][2] + ob4.z);
      const float g3 = sigm(acc[16 + nf][3] + ob4.w);
      uint2 gv; gv.x = pk2bf(g0, g1); gv.y = pk2bf(g2, g3);
      const int slot = (d0 >> 3) ^ (rloc & 7);
      *(uint2*)(ldsX + rloc * 128 + slot * 16 + (d0 & 4) * 2) = gv;
    }
  }
  __syncthreads();

  // coalesced stores: dense 16B per lane
  const int cx = c & 7;
  #pragma unroll
  for (int it = 0; it < 2; ++it) {
    const int idx = it * 512 + t;            // [0,1024)
    const int hh = idx >> 4, rel = idx & 15;
    const size_t goff = (size_t)hh * 524288 + (size_t)c * 1024 +
                        (size_t)(((r0 >> 3) + (rel & 8) + ((rel & 7) ^ cx)) << 4);
    *(uint4*)((char*)left_t  + goff) = *(const uint4*)(bL + hh * 272 + rel * 16);
    *(uint4*)((char*)right_t + goff) = *(const uint4*)(bR + hh * 272 + rel * 16);
  }
  // ogate -> [row][col][d]: per row a contiguous 128B run (8 chunks)
  #pragma unroll
  for (int it = 0; it < 2; ++it) {
    const int idx = it * 512 + t;            // [0,1024)
    const int rl = idx >> 3, ch = idx & 7;
    *(uint4*)((char*)ogate + ((size_t)(r0 + rl) * 512 + c) * 128 + ch * 16) =
        *(const uint4*)(ldsX + rl * 128 + ((ch ^ (rl & 7)) << 4));
  }
}

// ---------------- K2: einsum  o[d][i][j] = sum_k right_t[d][i][k]*left_t[d][j][k]
// 256x256 tiles. global_load_lds staging (linear dest = wave base + lane*16).
// XCD grouping: same-d quadrants dispatch to one XCD (share operand panels in
// its L2). Epilogue: bounce 128-row halves through dead LDS -> 16B stores in
// 512B segments instead of 128 scalar 2B scatters.
__global__ __launch_bounds__(512) void k2_einsum(
    const unsigned short* __restrict__ left_t,
    const unsigned short* __restrict__ right_t,
    unsigned short* __restrict__ o) {
  __shared__ __align__(16) char lds[69632];   // A[0:32K] B[32K:64K]; bounce [128][544]
  char* ldsA = lds;
  char* ldsB = lds + 32768;
  const int t = threadIdx.x;
  const int bid = (int)blockIdx.x;
  const int id = ((bid & 7) << 5) | (bid >> 3);  // round-robin slot -> XCD group
  const int d = id >> 2;
  const int i0 = ((id >> 1) & 1) * 256;
  const int j0 = (id & 1) * 256;
  const int w = t >> 6, l = t & 63, lr = l & 15, g = l >> 4;
  const char* Rb = (const char*)right_t + (size_t)d * 524288;
  const char* Lb = (const char*)left_t  + (size_t)d * 524288;
  f32x4 acc[8][4];
  #pragma unroll
  for (int mi = 0; mi < 8; ++mi)
    #pragma unroll
    for (int nj = 0; nj < 4; ++nj) acc[mi][nj] = (f32x4){0.f, 0.f, 0.f, 0.f};
  const int wm0 = (w >> 2) * 128, wn0 = (w & 3) * 64;
  for (int kb = 0; kb < 512; kb += 64) {
    // stage via global_load_lds: dest = (w*4+cc)*1024 + lane*16 (linear)
    #pragma unroll
    for (int cc = 0; cc < 4; ++cc) {
      const int p16 = (w * 4 + cc) * 64 + l;   // [0,2048)
      const int m = p16 >> 3, sl = p16 & 7;
      __builtin_amdgcn_global_load_lds(
          (const void*)(Rb + (size_t)(i0 + m) * 1024 + kb * 2 + sl * 16),
          (void*)(ldsA + p16 * 16), 16, 0, 0);
      __builtin_amdgcn_global_load_lds(
          (const void*)(Lb + (size_t)(j0 + m) * 1024 + kb * 2 + sl * 16),
          (void*)(ldsB + p16 * 16), 16, 0, 0);
    }
    __syncthreads();
    #pragma unroll
    for (int s = 0; s < 2; ++s) {
      const int soff = (((s * 4 + g) ^ (lr & 7)) << 4);
      bf16x8 af[8], bfr[4];
      #pragma unroll
      for (int mi = 0; mi < 8; ++mi)
        af[mi] = *(const bf16x8*)(ldsA + (wm0 + mi * 16 + lr) * 128 + soff);
      #pragma unroll
      for (int nj = 0; nj < 4; ++nj)
        bfr[nj] = *(const bf16x8*)(ldsB + (wn0 + nj * 16 + lr) * 128 + soff);
      #pragma unroll
      for (int mi = 0; mi < 8; ++mi)
        #pragma unroll
        for (int nj = 0; nj < 4; ++nj)
          acc[mi][nj] = __builtin_amdgcn_mfma_f32_16x16x32_bf16(
              af[mi], bfr[nj], acc[mi][nj], 0, 0, 0);
    }
    __syncthreads();
  }
  // epilogue: two 128-row halves bounced through LDS ([128][544], bank-clean)
  #pragma unroll
  for (int h2i = 0; h2i < 2; ++h2i) {
    if ((w >> 2) == h2i) {
      #pragma unroll
      for (int mi = 0; mi < 8; ++mi)
        #pragma unroll
        for (int nj = 0; nj < 4; ++nj)
          #pragma unroll
          for (int rr = 0; rr < 4; ++rr) {
            const int rl = mi * 16 + g * 4 + rr;       // local row in half
            const int col = wn0 + nj * 16 + lr;
            *(unsigned short*)(lds + rl * 544 + col * 2) = f2bf(acc[mi][nj][rr]);
          }
    }
    __syncthreads();
    #pragma unroll
    for (int it = 0; it < 8; ++it) {
      const int q = it * 512 + t;                      // [0,4096)
      const int rl = q >> 5, ch = q & 31;
      *(uint4*)((char*)o + (size_t)d * 524288 +
                (size_t)(i0 + h2i * 128 + rl) * 1024 + (size_t)j0 * 2 + ch * 16) =
          *(const uint4*)(lds + rl * 544 + ch * 16);
    }
    __syncthreads();
  }
}

// ---------------- K3: out-LN + out projection + out_gate ---------------------
// Direct-global LN reads (bit-identical values; 64B coalesced segments per
// d-plane, L3-resident, hoisted above W staging). No ldsO -> LDS ~10KB.
// Packed-f16 matvec with fp32 flush every 16 k.
__global__ __launch_bounds__(256) void k3_final(
    const unsigned short* __restrict__ o, const unsigned short* __restrict__ ogate,
    const float* __restrict__ onorm_w, const float* __restrict__ onorm_b,
    const float* __restrict__ out_w, const float* __restrict__ out_b,
    float* __restrict__ out) {
  __shared__ __align__(16) _Float16 ldsW[64 * 72];    // [64 k][64 n + 8 pad] f16
  __shared__ float sONW[64], sONB[64], sOB[64];
  const int t = threadIdx.x;
  const int i = blockIdx.x >> 2;
  const int j0 = (blockIdx.x & 3) << 7;
  const size_t p0 = (size_t)i * 512 + j0;
  const int p = t >> 1, h = t & 1;

  // LN input loads FIRST: latency hides under W staging + barrier.
  float v[32];
  {
    const unsigned short* op0 = o + (size_t)(h * 32) * 262144 + p0 + p;
    #pragma unroll
    for (int dl = 0; dl < 32; ++dl)
      v[dl] = bf2f(op0[(size_t)dl * 262144]);
  }

  // stage out_w as f16: ldsW[k*72+n]  (RNE; f16 rel err 2^-11, negligible)
  #pragma unroll
  for (int e = 0; e < 16; ++e) {
    const int idx = e * 256 + t;
    ldsW[(idx >> 6) * 72 + (idx & 63)] = (_Float16)out_w[idx];
  }
  if (t < 64) { sONW[t] = onorm_w[t]; sONB[t] = onorm_b[t]; sOB[t] = out_b[t]; }
  __syncthreads();

  // LN stats (pair reduce)
  float s = 0.f, ss = 0.f;
  #pragma unroll
  for (int dl = 0; dl < 32; ++dl) { s += v[dl]; ss += v[dl] * v[dl]; }
  s += __shfl_xor(s, 1); ss += __shfl_xor(ss, 1);
  const float mu = s * 0.015625f;
  const float rs = rsqrtf(ss * 0.015625f - mu * mu + 1e-5f);
  float xv[32];
  #pragma unroll
  for (int dl = 0; dl < 32; ++dl) {
    const int d = h * 32 + dl;
    xv[dl] = (v[dl] - mu) * rs * sONW[d] + sONB[d];
  }

  // matvec: out[p][n0..n0+31] = sum_k xn[p][k] * W[k][n], packed f16
  const int n0 = h * 32;
  _Float16 xA[32], xB[32];   // own k-half / partner k-half (static indexing)
  #pragma unroll
  for (int dl = 0; dl < 32; ++dl) {
    xA[dl] = (_Float16)xv[dl];
    xB[dl] = (_Float16)__shfl_xor(xv[dl], 1);
  }
  float acc[32];
  #pragma unroll
  for (int n = 0; n < 32; ++n) acc[n] = 0.f;
  const int kO = h * 32, kP = (1 - h) * 32;
  #pragma unroll
  for (int pb = 0; pb < 4; ++pb) {       // pb 0,1: own half; 2,3: partner half
    h2 acc2[16];
    #pragma unroll
    for (int n2 = 0; n2 < 16; ++n2) { acc2[n2][0] = (_Float16)0.f; acc2[n2][1] = (_Float16)0.f; }
    #pragma unroll
    for (int kk = 0; kk < 16; ++kk) {
      const int ko = (pb & 1) * 16 + kk;                 // compile-time
      const _Float16 av = (pb < 2) ? xA[ko] : xB[ko];    // compile-time select
      const int k = ((pb < 2) ? kO : kP) + ko;
      h2 a2; a2[0] = av; a2[1] = av;
      const uint4* wr = (const uint4*)(ldsW + k * 72 + n0);  // 144B rows, 16B-aligned
      const uint4 w0 = wr[0], w1 = wr[1], w2 = wr[2], w3 = wr[3];
      const unsigned wu[16] = {w0.x, w0.y, w0.z, w0.w, w1.x, w1.y, w1.z, w1.w,
                               w2.x, w2.y, w2.z, w2.w, w3.x, w3.y, w3.z, w3.w};
      #pragma unroll
      for (int n2 = 0; n2 < 16; ++n2)
        acc2[n2] = a2 * __builtin_bit_cast(h2, wu[n2]) + acc2[n2];  // v_pk_fma_f16
    }
    #pragma unroll
    for (int n2 = 0; n2 < 16; ++n2) {       // fp32 flush every 16 k
      acc[2 * n2]     += (float)acc2[n2][0];
      acc[2 * n2 + 1] += (float)acc2[n2][1];
    }
  }

  // epilogue: +out_b, *ogate (bf16, contiguous per position), fp32 store
  const size_t pl = p0 + p;
  const unsigned short* gp = ogate + pl * 64 + n0;
  float* op = out + pl * 64 + n0;
  #pragma unroll
  for (int c = 0; c < 4; ++c) {
    const uint4 g4 = *(const uint4*)(gp + c * 8);
    const unsigned gg[4] = {g4.x, g4.y, g4.z, g4.w};
    float r[8];
    #pragma unroll
    for (int e = 0; e < 4; ++e) {
      r[2*e]   = (acc[c*8 + 2*e]   + sOB[n0 + c*8 + 2*e])   *
                 bf2f((unsigned short)(gg[e] & 0xffffu));
      r[2*e+1] = (acc[c*8 + 2*e+1] + sOB[n0 + c*8 + 2*e+1]) *
                 bf2f((unsigned short)(gg[e] >> 16));
    }
    float4 s0; s0.x = r[0]; s0.y = r[1]; s0.z = r[2]; s0.w = r[3];
    float4 s1; s1.x = r[4]; s1.y = r[5]; s1.z = r[6]; s1.w = r[7];
    *(float4*)(op + c * 8)     = s0;
    *(float4*)(op + c * 8 + 4) = s1;
  }
}

extern "C" void kernel_launch(void* const* d_in, const int* in_sizes, int n_in,
                              void* d_out, int out_size, void* d_ws, size_t ws_size,
                              hipStream_t stream) {
  const float* x       = (const float*)d_in[0];
  const int*   sm      = (const int*)d_in[1];
  const float* norm_w  = (const float*)d_in[2];
  const float* norm_b  = (const float*)d_in[3];
  const float* left_w  = (const float*)d_in[4];
  const float* left_b  = (const float*)d_in[5];
  const float* right_w = (const float*)d_in[6];
  const float* right_b = (const float*)d_in[7];
  const float* lgate_w = (const float*)d_in[8];
  const float* lgate_b = (const float*)d_in[9];
  const float* rgate_w = (const float*)d_in[10];
  const float* rgate_b = (const float*)d_in[11];
  const float* ogate_w = (const float*)d_in[12];
  const float* ogate_b = (const float*)d_in[13];
  const float* onorm_w = (const float*)d_in[14];
  const float* onorm_b = (const float*)d_in[15];
  const float* out_w   = (const float*)d_in[16];
  const float* out_b   = (const float*)d_in[17];

  char* ws = (char*)d_ws;
  unsigned short* left_t  = (unsigned short*)(ws + 0);          // 33.5 MB
  unsigned short* right_t = (unsigned short*)(ws + 33554432);   // 33.5 MB
  unsigned short* ogate   = (unsigned short*)(ws + 67108864);   // 33.5 MB
  unsigned short* obuf    = (unsigned short*)(ws + 100663296);  // 33.5 MB
  unsigned short* wt      = (unsigned short*)(ws + 134217728);  // 40 KB

  if (ws_size < (size_t)134217728 + 40960) return;  // scratch too small

  k0_prep<<<dim3(20), dim3(256), 0, stream>>>(left_w, right_w, lgate_w, rgate_w,
                                              ogate_w, wt);
  k1_proj<<<dim3(2048), dim3(512), 0, stream>>>(x, sm, norm_w, norm_b, left_b,
                                                right_b, lgate_b, rgate_b,
                                                ogate_b, wt, left_t, right_t,
                                                ogate);
  k2_einsum<<<dim3(256), dim3(512), 0, stream>>>(left_t, right_t, obuf);
  k3_final<<<dim3(2048), dim3(256), 0, stream>>>(obuf, ogate, onorm_w, onorm_b,
                                                 out_w, out_b, (float*)d_out);
}

// Round 17
// 120.706 us; speedup vs baseline: 1.3189x; 1.0115x over previous
//
#include <hip/hip_runtime.h>

// TriangleMultiplicativeModule: B=1, L=512, D=H=64, fp32 in/out.
// FINAL (r14-best config): K0 weight prep -> K1 LN+5 proj (MFMA bf16,
// LDS-bounced coalesced stores) -> K2 einsum (64x batched 512^3 GEMM, MFMA
// bf16, 256^2 tiles, global_load_lds staging, XCD-grouped) -> K3 out-LN +
// out proj + gate (direct-global LN reads, packed-f16 matvec, fp32 flush).
//
// Global bf16 operand layouts are k-contiguous [h][col][k] with a baked XOR
// swizzle on 16B chunks within each 8-chunk (64-elem) window:
//   chunk position q of row holds k-chunk (q ^ (row&7))
// so LDS staging in K2 is a pure linear copy and ds_read_b128 fragment reads
// are bank-conflict-free.
// ogate layout: [row][col][d] (k3 reads contiguous; k1 stores via LDS bounce).
//
// Structural notes (measured, rounds 5-16):
//  - k1 ~70us: 165MB HBM (26us) + ~31us VALU + 4us MFMA across 6 barrier
//    phases at 2 blocks/CU. Six restructures (3-pass/2-pass acc splits,
//    global-B MFMA, async staging, barrier removal) all neutral or worse.
//    Zero inter-block reuse -> XCD swizzle inapplicable.
//  - k2 ~16us: operands L3-resident; global_load_lds + bounce epilogue +
//    XCD grouping were worth ~15us (r12).
//  - k3 ~25us vs 21us HBM floor: f16 packed matvec (r13) + no-stage (r14).

typedef __attribute__((ext_vector_type(4))) float f32x4;
typedef __attribute__((ext_vector_type(8))) __bf16 bf16x8;
typedef __attribute__((ext_vector_type(2))) _Float16 h2;

__device__ __forceinline__ unsigned short f2bf(float f) {
  unsigned u = __float_as_uint(f);
  u += 0x7FFFu + ((u >> 16) & 1u);   // RNE
  return (unsigned short)(u >> 16);
}
__device__ __forceinline__ float bf2f(unsigned short h) {
  return __uint_as_float(((unsigned)h) << 16);
}
// packed pair-convert: compiler lowers __bf16 casts to v_cvt_pk_bf16_f32 (RNE)
__device__ __forceinline__ unsigned pk2bf(float a, float b) {
  unsigned short ua = __builtin_bit_cast(unsigned short, (__bf16)a);
  unsigned short ub = __builtin_bit_cast(unsigned short, (__bf16)b);
  return (unsigned)ua | ((unsigned)ub << 16);
}
__device__ __forceinline__ float sigm(float x) { return 1.0f / (1.0f + __expf(-x)); }

// ---------------- K0: weight prep (20 blocks) ----------------
// wt[320][64] bf16: rows [left|right|lgate|rgate|ogate]; row n holds W[:,ch]
// k-contiguous, 16B chunks swizzled: pos q holds chunk q^(n&7).
__global__ __launch_bounds__(256) void k0_prep(
    const float* __restrict__ lw, const float* __restrict__ rw,
    const float* __restrict__ lgw, const float* __restrict__ rgw,
    const float* __restrict__ ogw, unsigned short* __restrict__ wt) {
  const int t0 = blockIdx.x * 1024 + threadIdx.x;
  #pragma unroll
  for (int e = 0; e < 4; ++e) {
    int idx = t0 + e * 256;  // [0, 20480)
    int n = idx >> 6, k = idx & 63;
    const float* W = (n < 64) ? lw : (n < 128) ? rw : (n < 192) ? lgw
                     : (n < 256) ? rgw : ogw;
    float v = W[k * 64 + (n & 63)];
    int el = n * 64 + ((((k >> 3) ^ (n & 7)) << 3) | (k & 7));
    wt[el] = f2bf(v);
  }
}

// ---------------- K1: LN + 5 projections + gates + mask (r10 form) ----------
// Block: 512 threads (8 waves), 128 positions (rows r0..r0+127 at fixed col c).
// Single-pass 20-frag MFMA. Epilogue bounces results through dead LDS so all
// global stores are dense 16B-per-lane runs.
__global__ __launch_bounds__(512) void k1_proj(
    const float* __restrict__ x, const int* __restrict__ smask,
    const float* __restrict__ norm_w, const float* __restrict__ norm_b,
    const float* __restrict__ left_b, const float* __restrict__ right_b,
    const float* __restrict__ lgate_b, const float* __restrict__ rgate_b,
    const float* __restrict__ ogate_b, const unsigned short* __restrict__ wt,
    unsigned short* __restrict__ left_t, unsigned short* __restrict__ right_t,
    unsigned short* __restrict__ ogate) {
  __shared__ __align__(16) char ldsWt[40960];  // weights; reused as L/R bounce
  __shared__ __align__(16) char ldsX[16384];   // xn swizzled; reused as OG bounce
  __shared__ float sNW[64], sNB[64];
  __shared__ __align__(16) float sLB[64], sRB[64], sLGB[64], sRGB[64], sOGB[64];
  __shared__ float sMK[128];

  const int t = threadIdx.x;
  const int c = blockIdx.x & 511;
  const int r0 = (blockIdx.x >> 9) << 7;

  // stage weights: linear copy (already swizzled in global)
  #pragma unroll
  for (int i = 0; i < 5; ++i) {
    int u = t + i * 512;
    *(uint4*)(ldsWt + u * 16) = *(const uint4*)((const char*)wt + u * 16);
  }
  if (t < 64) {
    sNW[t] = norm_w[t]; sNB[t] = norm_b[t];
    sLB[t] = left_b[t]; sRB[t] = right_b[t];
    sLGB[t] = lgate_b[t]; sRGB[t] = rgate_b[t]; sOGB[t] = ogate_b[t];
  }
  if (t >= 64 && t < 192) sMK[t - 64] = (float)smask[r0 + (t - 64)];
  __syncthreads();

  // phase 1: LayerNorm (4 threads/position, 16 ch each; 128 positions)
  {
    const int m = t >> 2, q = t & 3;
    const float* xp = x + ((size_t)(r0 + m) * 512 + c) * 64 + q * 16;
    float v[16];
    #pragma unroll
    for (int i = 0; i < 4; ++i) {
      float4 f = *(const float4*)(xp + i * 4);
      v[i*4+0] = f.x; v[i*4+1] = f.y; v[i*4+2] = f.z; v[i*4+3] = f.w;
    }
    float s = 0.f, ss = 0.f;
    #pragma unroll
    for (int i = 0; i < 16; ++i) { s += v[i]; ss += v[i] * v[i]; }
    s += __shfl_xor(s, 1); s += __shfl_xor(s, 2);
    ss += __shfl_xor(ss, 1); ss += __shfl_xor(ss, 2);
    const float mu = s * 0.015625f;
    const float rs = rsqrtf(ss * 0.015625f - mu * mu + 1e-5f);
    unsigned pk[8];
    #pragma unroll
    for (int i = 0; i < 8; ++i) {
      const int d0 = q * 16 + 2 * i;
      pk[i] = pk2bf((v[2*i]   - mu) * rs * sNW[d0]     + sNB[d0],
                    (v[2*i+1] - mu) * rs * sNW[d0 + 1] + sNB[d0 + 1]);
    }
    uint4 lo; lo.x = pk[0]; lo.y = pk[1]; lo.z = pk[2]; lo.w = pk[3];
    uint4 hi; hi.x = pk[4]; hi.y = pk[5]; hi.z = pk[6]; hi.w = pk[7];
    *(uint4*)(ldsX + m * 128 + (((q * 2)     ^ (m & 7)) << 4)) = lo;
    *(uint4*)(ldsX + m * 128 + (((q * 2 + 1) ^ (m & 7)) << 4)) = hi;
  }
  __syncthreads();

  // phase 2: MFMA  out[m][n] = xn[m][k] @ W[k][n], n in [0,320)
  // nf 0..15: D[pos][n] (A=xn, B=W). nf 16..19 (ogate): SWAPPED -> D[d][pos].
  const int w = t >> 6, l = t & 63, lr = l & 15, g = l >> 4;
  f32x4 acc[20];
  #pragma unroll
  for (int nf = 0; nf < 20; ++nf) acc[nf] = (f32x4){0.f, 0.f, 0.f, 0.f};
  const int rowA = w * 16 + lr;
  #pragma unroll
  for (int s = 0; s < 2; ++s) {
    const int soff = (((s * 4 + g) ^ (lr & 7)) << 4);
    bf16x8 a = *(const bf16x8*)(ldsX + rowA * 128 + soff);
    #pragma unroll
    for (int nf = 0; nf < 16; ++nf) {
      bf16x8 bb = *(const bf16x8*)(ldsWt + (nf * 16 + lr) * 128 + soff);
      acc[nf] = __builtin_amdgcn_mfma_f32_16x16x32_bf16(a, bb, acc[nf], 0, 0, 0);
    }
    #pragma unroll
    for (int nf = 16; nf < 20; ++nf) {
      bf16x8 bb = *(const bf16x8*)(ldsWt + (nf * 16 + lr) * 128 + soff);
      acc[nf] = __builtin_amdgcn_mfma_f32_16x16x32_bf16(bb, a, acc[nf], 0, 0, 0);
    }
  }
  __syncthreads();   // all MFMA LDS reads done -> ldsWt/ldsX reusable

  // epilogue compute -> LDS bounce
  char* bL = ldsWt;            // [64 ch][272B] (128 pos bf16 + 16B pad)
  char* bR = ldsWt + 17408;    // [64 ch][272B]
  {
    const float mc = (float)smask[c];
    float mk[4];
    #pragma unroll
    for (int rr = 0; rr < 4; ++rr) mk[rr] = mc * sMK[w * 16 + g * 4 + rr];
    const int rb2 = (w * 16 + g * 4) * 2;
    #pragma unroll
    for (int nf = 0; nf < 4; ++nf) {
      const int hh = nf * 16 + lr;
      const float lb = sLB[hh], rb = sRB[hh];
      const float lgb = sLGB[hh], rgb = sRGB[hh];
      float lo[4], ro[4];
      #pragma unroll
      for (int rr = 0; rr < 4; ++rr) {
        lo[rr] = (acc[nf][rr]     + lb) * mk[rr] * sigm(acc[8  + nf][rr] + lgb);
        ro[rr] = (acc[4 + nf][rr] + rb) * mk[rr] * sigm(acc[12 + nf][rr] + rgb);
      }
      uint2 lv; lv.x = pk2bf(lo[0], lo[1]); lv.y = pk2bf(lo[2], lo[3]);
      uint2 rv; rv.x = pk2bf(ro[0], ro[1]); rv.y = pk2bf(ro[2], ro[3]);
      *(uint2*)(bL + hh * 272 + rb2) = lv;
      *(uint2*)(bR + hh * 272 + rb2) = rv;
    }
    // ogate bounce: [128 r][64 d] in ldsX, 16B chunks XOR-swizzled by (r&7)
    const int rloc = w * 16 + lr;
    #pragma unroll
    for (int nf = 0; nf < 4; ++nf) {
      const int d0 = nf * 16 + g * 4;
      const float4 ob4 = *(const float4*)&sOGB[d0];
      const float g0 = sigm(acc[16 + nf][0] + ob4.x);
      const float g1 = sigm(acc[16 + nf][1] + ob4.y);
      const float g2 = sigm(acc[16 + nf][2] + ob4.z);
      const float g3 = sigm(acc[16 + nf][3] + ob4.w);
      uint2 gv; gv.x = pk2bf(g0, g1); gv.y = pk2bf(g2, g3);
      const int slot = (d0 >> 3) ^ (rloc & 7);
      *(uint2*)(ldsX + rloc * 128 + slot * 16 + (d0 & 4) * 2) = gv;
    }
  }
  __syncthreads();

  // coalesced stores: dense 16B per lane
  const int cx = c & 7;
  #pragma unroll
  for (int it = 0; it < 2; ++it) {
    const int idx = it * 512 + t;            // [0,1024)
    const int hh = idx >> 4, rel = idx & 15;
    const size_t goff = (size_t)hh * 524288 + (size_t)c * 1024 +
                        (size_t)(((r0 >> 3) + (rel & 8) + ((rel & 7) ^ cx)) << 4);
    *(uint4*)((char*)left_t  + goff) = *(const uint4*)(bL + hh * 272 + rel * 16);
    *(uint4*)((char*)right_t + goff) = *(const uint4*)(bR + hh * 272 + rel * 16);
  }
  // ogate -> [row][col][d]: per row a contiguous 128B run (8 chunks)
  #pragma unroll
  for (int it = 0; it < 2; ++it) {
    const int idx = it * 512 + t;            // [0,1024)
    const int rl = idx >> 3, ch = idx & 7;
    *(uint4*)((char*)ogate + ((size_t)(r0 + rl) * 512 + c) * 128 + ch * 16) =
        *(const uint4*)(ldsX + rl * 128 + ((ch ^ (rl & 7)) << 4));
  }
}

// ---------------- K2: einsum  o[d][i][j] = sum_k right_t[d][i][k]*left_t[d][j][k]
// 256x256 tiles. global_load_lds staging (linear dest = wave base + lane*16).
// XCD grouping: same-d quadrants dispatch to one XCD (share operand panels in
// its L2). Epilogue: bounce 128-row halves through dead LDS -> 16B stores in
// 512B segments instead of 128 scalar 2B scatters.
__global__ __launch_bounds__(512) void k2_einsum(
    const unsigned short* __restrict__ left_t,
    const unsigned short* __restrict__ right_t,
    unsigned short* __restrict__ o) {
  __shared__ __align__(16) char lds[69632];   // A[0:32K] B[32K:64K]; bounce [128][544]
  char* ldsA = lds;
  char* ldsB = lds + 32768;
  const int t = threadIdx.x;
  const int bid = (int)blockIdx.x;
  const int id = ((bid & 7) << 5) | (bid >> 3);  // round-robin slot -> XCD group
  const int d = id >> 2;
  const int i0 = ((id >> 1) & 1) * 256;
  const int j0 = (id & 1) * 256;
  const int w = t >> 6, l = t & 63, lr = l & 15, g = l >> 4;
  const char* Rb = (const char*)right_t + (size_t)d * 524288;
  const char* Lb = (const char*)left_t  + (size_t)d * 524288;
  f32x4 acc[8][4];
  #pragma unroll
  for (int mi = 0; mi < 8; ++mi)
    #pragma unroll
    for (int nj = 0; nj < 4; ++nj) acc[mi][nj] = (f32x4){0.f, 0.f, 0.f, 0.f};
  const int wm0 = (w >> 2) * 128, wn0 = (w & 3) * 64;
  for (int kb = 0; kb < 512; kb += 64) {
    // stage via global_load_lds: dest = (w*4+cc)*1024 + lane*16 (linear)
    #pragma unroll
    for (int cc = 0; cc < 4; ++cc) {
      const int p16 = (w * 4 + cc) * 64 + l;   // [0,2048)
      const int m = p16 >> 3, sl = p16 & 7;
      __builtin_amdgcn_global_load_lds(
          (const void*)(Rb + (size_t)(i0 + m) * 1024 + kb * 2 + sl * 16),
          (void*)(ldsA + p16 * 16), 16, 0, 0);
      __builtin_amdgcn_global_load_lds(
          (const void*)(Lb + (size_t)(j0 + m) * 1024 + kb * 2 + sl * 16),
          (void*)(ldsB + p16 * 16), 16, 0, 0);
    }
    __syncthreads();
    #pragma unroll
    for (int s = 0; s < 2; ++s) {
      const int soff = (((s * 4 + g) ^ (lr & 7)) << 4);
      bf16x8 af[8], bfr[4];
      #pragma unroll
      for (int mi = 0; mi < 8; ++mi)
        af[mi] = *(const bf16x8*)(ldsA + (wm0 + mi * 16 + lr) * 128 + soff);
      #pragma unroll
      for (int nj = 0; nj < 4; ++nj)
        bfr[nj] = *(const bf16x8*)(ldsB + (wn0 + nj * 16 + lr) * 128 + soff);
      #pragma unroll
      for (int mi = 0; mi < 8; ++mi)
        #pragma unroll
        for (int nj = 0; nj < 4; ++nj)
          acc[mi][nj] = __builtin_amdgcn_mfma_f32_16x16x32_bf16(
              af[mi], bfr[nj], acc[mi][nj], 0, 0, 0);
    }
    __syncthreads();
  }
  // epilogue: two 128-row halves bounced through LDS ([128][544], bank-clean)
  #pragma unroll
  for (int h2i = 0; h2i < 2; ++h2i) {
    if ((w >> 2) == h2i) {
      #pragma unroll
      for (int mi = 0; mi < 8; ++mi)
        #pragma unroll
        for (int nj = 0; nj < 4; ++nj)
          #pragma unroll
          for (int rr = 0; rr < 4; ++rr) {
            const int rl = mi * 16 + g * 4 + rr;       // local row in half
            const int col = wn0 + nj * 16 + lr;
            *(unsigned short*)(lds + rl * 544 + col * 2) = f2bf(acc[mi][nj][rr]);
          }
    }
    __syncthreads();
    #pragma unroll
    for (int it = 0; it < 8; ++it) {
      const int q = it * 512 + t;                      // [0,4096)
      const int rl = q >> 5, ch = q & 31;
      *(uint4*)((char*)o + (size_t)d * 524288 +
                (size_t)(i0 + h2i * 128 + rl) * 1024 + (size_t)j0 * 2 + ch * 16) =
          *(const uint4*)(lds + rl * 544 + ch * 16);
    }
    __syncthreads();
  }
}

// ---------------- K3: out-LN + out projection + out_gate ---------------------
// Direct-global LN reads (bit-identical values; 64B coalesced segments per
// d-plane, L3-resident, hoisted above W staging). No ldsO -> LDS ~10KB.
// Packed-f16 matvec with fp32 flush every 16 k.
__global__ __launch_bounds__(256) void k3_final(
    const unsigned short* __restrict__ o, const unsigned short* __restrict__ ogate,
    const float* __restrict__ onorm_w, const float* __restrict__ onorm_b,
    const float* __restrict__ out_w, const float* __restrict__ out_b,
    float* __restrict__ out) {
  __shared__ __align__(16) _Float16 ldsW[64 * 72];    // [64 k][64 n + 8 pad] f16
  __shared__ float sONW[64], sONB[64], sOB[64];
  const int t = threadIdx.x;
  const int i = blockIdx.x >> 2;
  const int j0 = (blockIdx.x & 3) << 7;
  const size_t p0 = (size_t)i * 512 + j0;
  const int p = t >> 1, h = t & 1;

  // LN input loads FIRST: latency hides under W staging + barrier.
  float v[32];
  {
    const unsigned short* op0 = o + (size_t)(h * 32) * 262144 + p0 + p;
    #pragma unroll
    for (int dl = 0; dl < 32; ++dl)
      v[dl] = bf2f(op0[(size_t)dl * 262144]);
  }

  // stage out_w as f16: ldsW[k*72+n]  (RNE; f16 rel err 2^-11, negligible)
  #pragma unroll
  for (int e = 0; e < 16; ++e) {
    const int idx = e * 256 + t;
    ldsW[(idx >> 6) * 72 + (idx & 63)] = (_Float16)out_w[idx];
  }
  if (t < 64) { sONW[t] = onorm_w[t]; sONB[t] = onorm_b[t]; sOB[t] = out_b[t]; }
  __syncthreads();

  // LN stats (pair reduce)
  float s = 0.f, ss = 0.f;
  #pragma unroll
  for (int dl = 0; dl < 32; ++dl) { s += v[dl]; ss += v[dl] * v[dl]; }
  s += __shfl_xor(s, 1); ss += __shfl_xor(ss, 1);
  const float mu = s * 0.015625f;
  const float rs = rsqrtf(ss * 0.015625f - mu * mu + 1e-5f);
  float xv[32];
  #pragma unroll
  for (int dl = 0; dl < 32; ++dl) {
    const int d = h * 32 + dl;
    xv[dl] = (v[dl] - mu) * rs * sONW[d] + sONB[d];
  }

  // matvec: out[p][n0..n0+31] = sum_k xn[p][k] * W[k][n], packed f16
  const int n0 = h * 32;
  _Float16 xA[32], xB[32];   // own k-half / partner k-half (static indexing)
  #pragma unroll
  for (int dl = 0; dl < 32; ++dl) {
    xA[dl] = (_Float16)xv[dl];
    xB[dl] = (_Float16)__shfl_xor(xv[dl], 1);
  }
  float acc[32];
  #pragma unroll
  for (int n = 0; n < 32; ++n) acc[n] = 0.f;
  const int kO = h * 32, kP = (1 - h) * 32;
  #pragma unroll
  for (int pb = 0; pb < 4; ++pb) {       // pb 0,1: own half; 2,3: partner half
    h2 acc2[16];
    #pragma unroll
    for (int n2 = 0; n2 < 16; ++n2) { acc2[n2][0] = (_Float16)0.f; acc2[n2][1] = (_Float16)0.f; }
    #pragma unroll
    for (int kk = 0; kk < 16; ++kk) {
      const int ko = (pb & 1) * 16 + kk;                 // compile-time
      const _Float16 av = (pb < 2) ? xA[ko] : xB[ko];    // compile-time select
      const int k = ((pb < 2) ? kO : kP) + ko;
      h2 a2; a2[0] = av; a2[1] = av;
      const uint4* wr = (const uint4*)(ldsW + k * 72 + n0);  // 144B rows, 16B-aligned
      const uint4 w0 = wr[0], w1 = wr[1], w2 = wr[2], w3 = wr[3];
      const unsigned wu[16] = {w0.x, w0.y, w0.z, w0.w, w1.x, w1.y, w1.z, w1.w,
                               w2.x, w2.y, w2.z, w2.w, w3.x, w3.y, w3.z, w3.w};
      #pragma unroll
      for (int n2 = 0; n2 < 16; ++n2)
        acc2[n2] = a2 * __builtin_bit_cast(h2, wu[n2]) + acc2[n2];  // v_pk_fma_f16
    }
    #pragma unroll
    for (int n2 = 0; n2 < 16; ++n2) {       // fp32 flush every 16 k
      acc[2 * n2]     += (float)acc2[n2][0];
      acc[2 * n2 + 1] += (float)acc2[n2][1];
    }
  }

  // epilogue: +out_b, *ogate (bf16, contiguous per position), fp32 store
  const size_t pl = p0 + p;
  const unsigned short* gp = ogate + pl * 64 + n0;
  float* op = out + pl * 64 + n0;
  #pragma unroll
  for (int c = 0; c < 4; ++c) {
    const uint4 g4 = *(const uint4*)(gp + c * 8);
    const unsigned gg[4] = {g4.x, g4.y, g4.z, g4.w};
    float r[8];
    #pragma unroll
    for (int e = 0; e < 4; ++e) {
      r[2*e]   = (acc[c*8 + 2*e]   + sOB[n0 + c*8 + 2*e])   *
                 bf2f((unsigned short)(gg[e] & 0xffffu));
      r[2*e+1] = (acc[c*8 + 2*e+1] + sOB[n0 + c*8 + 2*e+1]) *
                 bf2f((unsigned short)(gg[e] >> 16));
    }
    float4 s0; s0.x = r[0]; s0.y = r[1]; s0.z = r[2]; s0.w = r[3];
    float4 s1; s1.x = r[4]; s1.y = r[5]; s1.z = r[6]; s1.w = r[7];
    *(float4*)(op + c * 8)     = s0;
    *(float4*)(op + c * 8 + 4) = s1;
  }
}

extern "C" void kernel_launch(void* const* d_in, const int* in_sizes, int n_in,
                              void* d_out, int out_size, void* d_ws, size_t ws_size,
                              hipStream_t stream) {
  const float* x       = (const float*)d_in[0];
  const int*   sm      = (const int*)d_in[1];
  const float* norm_w  = (const float*)d_in[2];
  const float* norm_b  = (const float*)d_in[3];
  const float* left_w  = (const float*)d_in[4];
  const float* left_b  = (const float*)d_in[5];
  const float* right_w = (const float*)d_in[6];
  const float* right_b = (const float*)d_in[7];
  const float* lgate_w = (const float*)d_in[8];
  const float* lgate_b = (const float*)d_in[9];
  const float* rgate_w = (const float*)d_in[10];
  const float* rgate_b = (const float*)d_in[11];
  const float* ogate_w = (const float*)d_in[12];
  const float* ogate_b = (const float*)d_in[13];
  const float* onorm_w = (const float*)d_in[14];
  const float* onorm_b = (const float*)d_in[15];
  const float* out_w   = (const float*)d_in[16];
  const float* out_b   = (const float*)d_in[17];

  char* ws = (char*)d_ws;
  unsigned short* left_t  = (unsigned short*)(ws + 0);          // 33.5 MB
  unsigned short* right_t = (unsigned short*)(ws + 33554432);   // 33.5 MB
  unsigned short* ogate   = (unsigned short*)(ws + 67108864);   // 33.5 MB
  unsigned short* obuf    = (unsigned short*)(ws + 100663296);  // 33.5 MB
  unsigned short* wt      = (unsigned short*)(ws + 134217728);  // 40 KB

  if (ws_size < (size_t)134217728 + 40960) return;  // scratch too small

  k0_prep<<<dim3(20), dim3(256), 0, stream>>>(left_w, right_w, lgate_w, rgate_w,
                                              ogate_w, wt);
  k1_proj<<<dim3(2048), dim3(512), 0, stream>>>(x, sm, norm_w, norm_b, left_b,
                                                right_b, lgate_b, rgate_b,
                                                ogate_b, wt, left_t, right_t,
                                                ogate);
  k2_einsum<<<dim3(256), dim3(512), 0, stream>>>(left_t, right_t, obuf);
  k3_final<<<dim3(2048), dim3(256), 0, stream>>>(obuf, ogate, onorm_w, onorm_b,
                                                 out_w, out_b, (float*)d_out);
}